// Round 2
// baseline (36.769 us; speedup 1.0000x reference)
//
#include <hip/hip_runtime.h>

#define N_NODES 4096
#define DEG 8
#define N_EDGES (N_NODES * DEG)
#define FEAT 64
#define HID 32
#define N_CLASSES 2
#define N_SEEDS 512

// Z1[n][h] = sum_k X[n][k] * W1[k][h]
__global__ void gemm1_kernel(const float* __restrict__ X,
                             const float* __restrict__ W1,
                             float* __restrict__ Z1) {
    __shared__ float W1s[FEAT * HID];
    int tid = threadIdx.x;
    for (int i = tid; i < FEAT * HID; i += blockDim.x) W1s[i] = W1[i];
    __syncthreads();
    int idx = blockIdx.x * blockDim.x + tid;   // n*32 + h
    int n = idx >> 5, h = idx & 31;
    const float* xrow = X + n * FEAT;
    float acc = 0.f;
#pragma unroll
    for (int k = 0; k < FEAT; ++k) acc += xrow[k] * W1s[k * HID + h];
    Z1[idx] = acc;
}

// Per edge e, per hidden dim h: m = Z1[u]+Z1[v] (dedup if u==v); scatter to both.
__global__ void edge1_kernel(const float* __restrict__ Z1,
                             const int* __restrict__ ind,
                             float* __restrict__ A1) {
    int idx = blockIdx.x * blockDim.x + threadIdx.x;  // e*32 + h
    int e = idx >> 5, h = idx & 31;
    int u = e >> 3;            // uniform CSR: indptr[n] = n*DEG
    int v = ind[e];
    float m = Z1[u * HID + h];
    if (v != u) m += Z1[v * HID + h];
    atomicAdd(&A1[u * HID + h], m);
    if (v != u) atomicAdd(&A1[v * HID + h], m);
}

// Z2[n][c] = sum_k relu(A1[n][k]+b1[k]) * W2[k][c]
__global__ void layer2_kernel(const float* __restrict__ A1,
                              const float* __restrict__ b1,
                              const float* __restrict__ W2,
                              float* __restrict__ Z2) {
    int n = blockIdx.x * blockDim.x + threadIdx.x;
    if (n >= N_NODES) return;
    float z0 = 0.f, z1 = 0.f;
#pragma unroll
    for (int k = 0; k < HID; ++k) {
        float hk = A1[n * HID + k] + b1[k];
        hk = hk > 0.f ? hk : 0.f;
        z0 += hk * W2[k * N_CLASSES + 0];
        z1 += hk * W2[k * N_CLASSES + 1];
    }
    Z2[n * N_CLASSES + 0] = z0;
    Z2[n * N_CLASSES + 1] = z1;
}

__global__ void edge2_kernel(const float* __restrict__ Z2,
                             const int* __restrict__ ind,
                             float* __restrict__ A2) {
    int idx = blockIdx.x * blockDim.x + threadIdx.x;  // e*2 + c
    int e = idx >> 1, c = idx & 1;
    int u = e >> 3;
    int v = ind[e];
    float m = Z2[u * N_CLASSES + c];
    if (v != u) m += Z2[v * N_CLASSES + c];
    atomicAdd(&A2[u * N_CLASSES + c], m);
    if (v != u) atomicAdd(&A2[v * N_CLASSES + c], m);
}

__global__ void out_kernel(const float* __restrict__ A2,
                           const float* __restrict__ b2,
                           const int* __restrict__ seed,
                           float* __restrict__ out) {
    int idx = blockIdx.x * blockDim.x + threadIdx.x;  // s*2 + c
    if (idx >= N_SEEDS * N_CLASSES) return;
    int s = idx >> 1, c = idx & 1;
    out[idx] = A2[seed[s] * N_CLASSES + c] + b2[c];
}

extern "C" void kernel_launch(void* const* d_in, const int* in_sizes, int n_in,
                              void* d_out, int out_size, void* d_ws, size_t ws_size,
                              hipStream_t stream) {
    // setup_inputs order: sub_indptr, sub_indices, X, W1, b1, W2, b2, seed_idx
    const int*   ind  = (const int*)d_in[1];
    const float* X    = (const float*)d_in[2];
    const float* W1   = (const float*)d_in[3];
    const float* b1   = (const float*)d_in[4];
    const float* W2   = (const float*)d_in[5];
    const float* b2   = (const float*)d_in[6];
    const int*   seed = (const int*)d_in[7];
    float* out = (float*)d_out;

    char* ws = (char*)d_ws;
    float* Z1 = (float*)(ws);                            // 4096*32*4 = 512 KiB
    float* A1 = (float*)(ws + 512 * 1024);               // 512 KiB
    float* Z2 = (float*)(ws + 1024 * 1024);              // 32 KiB
    float* A2 = (float*)(ws + 1024 * 1024 + 32 * 1024);  // 32 KiB

    hipMemsetAsync(A1, 0, N_NODES * HID * sizeof(float), stream);
    hipMemsetAsync(A2, 0, N_NODES * N_CLASSES * sizeof(float), stream);

    gemm1_kernel<<<(N_NODES * HID) / 256, 256, 0, stream>>>(X, W1, Z1);
    edge1_kernel<<<(N_EDGES * HID) / 256, 256, 0, stream>>>(Z1, ind, A1);
    layer2_kernel<<<(N_NODES + 255) / 256, 256, 0, stream>>>(A1, b1, W2, Z2);
    edge2_kernel<<<(N_EDGES * N_CLASSES) / 256, 256, 0, stream>>>(Z2, ind, A2);
    out_kernel<<<(N_SEEDS * N_CLASSES + 255) / 256, 256, 0, stream>>>(A2, b2, seed, out);
}

// Round 3
// 35.727 us; speedup vs baseline: 1.0292x; 1.0292x over previous
//
#include <hip/hip_runtime.h>

#define N_NODES 4096
#define DEG 8
#define N_EDGES (N_NODES * DEG)
#define FEAT 64
#define HID 32
#define N_CLASSES 2
#define N_SEEDS 512

// K1: Z1 = X@W1, plus zero-init A1 (131072 floats == thread count) and A2.
__global__ void k1_gemm_init(const float* __restrict__ X,
                             const float* __restrict__ W1,
                             float* __restrict__ Z1,
                             float* __restrict__ A1,
                             float* __restrict__ A2) {
    __shared__ float W1s[FEAT * HID];
    int tid = threadIdx.x;
    for (int i = tid; i < FEAT * HID; i += blockDim.x) W1s[i] = W1[i];
    __syncthreads();
    int idx = blockIdx.x * blockDim.x + tid;   // n*32 + h, 0..131071
    int n = idx >> 5, h = idx & 31;
    const float* xrow = X + n * FEAT;
    float acc = 0.f;
#pragma unroll
    for (int k = 0; k < FEAT; ++k) acc += xrow[k] * W1s[k * HID + h];
    Z1[idx] = acc;
    A1[idx] = 0.f;
    if (idx < N_NODES * N_CLASSES) A2[idx] = 0.f;
}

// K2: per (node n, hidden h): own-edge messages summed in register (1 atomic),
// reverse contributions scattered atomically. Matches inc@(inc.T@Z1) with dedup.
__global__ void k2_edge1(const float* __restrict__ Z1,
                         const int* __restrict__ ind,
                         float* __restrict__ A1) {
    int idx = blockIdx.x * blockDim.x + threadIdx.x;  // n*32 + h
    int n = idx >> 5, h = idx & 31;
    float zn = Z1[n * HID + h];
    float own = 0.f;
    const int* row = ind + n * DEG;
#pragma unroll
    for (int d = 0; d < DEG; ++d) {
        int v = row[d];
        if (v == n) {
            own += zn;                       // self-loop edge counted once
        } else {
            float m = zn + Z1[v * HID + h];
            own += m;
            atomicAdd(&A1[v * HID + h], m);  // reverse scatter
        }
    }
    atomicAdd(&A1[n * HID + h], own);
}

__device__ inline void z2_of(const float* __restrict__ A1,
                             const float* __restrict__ b1,
                             const float* __restrict__ W2,
                             int n, float& z0, float& z1) {
    z0 = 0.f; z1 = 0.f;
    const float4* a = (const float4*)(A1 + n * HID);
#pragma unroll
    for (int q = 0; q < HID / 4; ++q) {
        float4 av = a[q];
        float vals[4] = {av.x, av.y, av.z, av.w};
#pragma unroll
        for (int j = 0; j < 4; ++j) {
            int k = q * 4 + j;
            float hk = vals[j] + b1[k];
            hk = hk > 0.f ? hk : 0.f;
            z0 += hk * W2[k * N_CLASSES + 0];
            z1 += hk * W2[k * N_CLASSES + 1];
        }
    }
}

// K3: fused layer2 + edge2. One thread per node: recompute Z2[n] and Z2[v]
// per neighbor; own contributions in register, reverse via atomics.
__global__ void k3_edge2(const float* __restrict__ A1,
                         const float* __restrict__ b1,
                         const float* __restrict__ W2,
                         const int* __restrict__ ind,
                         float* __restrict__ A2) {
    int n = blockIdx.x * blockDim.x + threadIdx.x;
    if (n >= N_NODES) return;
    float zn0, zn1;
    z2_of(A1, b1, W2, n, zn0, zn1);
    float own0 = 0.f, own1 = 0.f;
    const int* row = ind + n * DEG;
#pragma unroll
    for (int d = 0; d < DEG; ++d) {
        int v = row[d];
        if (v == n) {
            own0 += zn0; own1 += zn1;
        } else {
            float zv0, zv1;
            z2_of(A1, b1, W2, v, zv0, zv1);
            float m0 = zn0 + zv0, m1 = zn1 + zv1;
            own0 += m0; own1 += m1;
            atomicAdd(&A2[v * N_CLASSES + 0], m0);
            atomicAdd(&A2[v * N_CLASSES + 1], m1);
        }
    }
    atomicAdd(&A2[n * N_CLASSES + 0], own0);
    atomicAdd(&A2[n * N_CLASSES + 1], own1);
}

// K4: seed gather + b2.
__global__ void k4_out(const float* __restrict__ A2,
                       const float* __restrict__ b2,
                       const int* __restrict__ seed,
                       float* __restrict__ out) {
    int idx = blockIdx.x * blockDim.x + threadIdx.x;  // s*2 + c
    if (idx >= N_SEEDS * N_CLASSES) return;
    int s = idx >> 1, c = idx & 1;
    out[idx] = A2[seed[s] * N_CLASSES + c] + b2[c];
}

extern "C" void kernel_launch(void* const* d_in, const int* in_sizes, int n_in,
                              void* d_out, int out_size, void* d_ws, size_t ws_size,
                              hipStream_t stream) {
    // setup_inputs order: sub_indptr, sub_indices, X, W1, b1, W2, b2, seed_idx
    const int*   ind  = (const int*)d_in[1];
    const float* X    = (const float*)d_in[2];
    const float* W1   = (const float*)d_in[3];
    const float* b1   = (const float*)d_in[4];
    const float* W2   = (const float*)d_in[5];
    const float* b2   = (const float*)d_in[6];
    const int*   seed = (const int*)d_in[7];
    float* out = (float*)d_out;

    char* ws = (char*)d_ws;
    float* Z1 = (float*)(ws);                            // 512 KiB
    float* A1 = (float*)(ws + 512 * 1024);               // 512 KiB
    float* A2 = (float*)(ws + 1024 * 1024);              // 32 KiB

    k1_gemm_init<<<(N_NODES * HID) / 256, 256, 0, stream>>>(X, W1, Z1, A1, A2);
    k2_edge1<<<(N_NODES * HID) / 256, 256, 0, stream>>>(Z1, ind, A1);
    k3_edge2<<<(N_NODES + 255) / 256, 256, 0, stream>>>(A1, b1, W2, ind, A2);
    k4_out<<<(N_SEEDS * N_CLASSES + 255) / 256, 256, 0, stream>>>(A2, b2, seed, out);
}